// Round 2
// baseline (910.391 us; speedup 1.0000x reference)
//
#include <hip/hip_runtime.h>
#include <math.h>

// ---------------------------------------------------------------------------
// GAT encoder: 3 GATConv layers (H=4,4,1) + ELU + global max pool.
// CSR-by-dst build (count/scan/scatter) once per call, then per layer:
//   gemm_att:  z = h @ W  (fp32, LDS-tiled, k-by-4), fused a_s/a_d epilogue
//   aggregate: per-node softmax (no max pass - exp args are O(10), fp32-safe)
//              + 4-deep pipelined weighted gather
// Final: encoded atomicMax segment pool + decode.
// ---------------------------------------------------------------------------

__device__ __forceinline__ float lrelu(float x) { return x > 0.f ? x : 0.2f * x; }

// ----------------------------- CSR build -----------------------------------
__global__ void k_count(const int* __restrict__ dst, int E, int* __restrict__ deg) {
    int e = blockIdx.x * 256 + threadIdx.x;
    if (e < E) atomicAdd(&deg[dst[e]], 1);
}

__global__ void k_scan(const int* __restrict__ deg, int* __restrict__ rowptr,
                       int* __restrict__ cursor, int N) {
    __shared__ int sums[1024];
    const int t = threadIdx.x;
    const int per = (N + 1023) >> 10;
    const int b0 = t * per;
    const int b1 = min(b0 + per, N);
    int s = 0;
    for (int i = b0; i < b1; i++) s += deg[i];
    sums[t] = s;
    __syncthreads();
    for (int off = 1; off < 1024; off <<= 1) {
        int v = (t >= off) ? sums[t - off] : 0;
        __syncthreads();
        sums[t] += v;
        __syncthreads();
    }
    int run = (t == 0) ? 0 : sums[t - 1];
    for (int i = b0; i < b1; i++) {
        rowptr[i] = run;
        cursor[i] = run;
        run += deg[i];
    }
    if (t == 1023) rowptr[N] = sums[1023];
}

__global__ void k_scatter(const int* __restrict__ src, const int* __restrict__ dst, int E,
                          int* __restrict__ cursor, int* __restrict__ col) {
    int e = blockIdx.x * 256 + threadIdx.x;
    if (e < E) {
        int p = atomicAdd(&cursor[dst[e]], 1);
        col[p] = src[e];
    }
}

// ----------------------------- GEMM + attention coefs -----------------------
// Z[N,COLS] = X[N,K] @ W[K,COLS]; a_s[n,h] = <z[n,h,:], att_src[h,:]>, same a_d.
// BM rows/block, 256 threads. Thread owns 4 cols (c4) x RPG rows (interleaved
// by NG). LDS x-tile reads are full-wave broadcasts (COLS=256) or 4-address
// (COLS=64) -> conflict-free. Inner loop: 4 k-steps per iteration.
template <int K, int COLS, int BM>
__global__ __launch_bounds__(256) void k_gemm_att(
    const float* __restrict__ X, const float* __restrict__ W,
    const float* __restrict__ att_src, const float* __restrict__ att_dst,
    float* __restrict__ Z, float* __restrict__ As, float* __restrict__ Ad, int N) {
    constexpr int C4 = COLS / 4;     // threads per row-strip
    constexpr int NG = 256 / C4;     // row groups
    constexpr int RPG = BM / NG;     // rows per thread
    constexpr int BK = 64;
    constexpr int SK = BK + 4;       // LDS stride (floats), keeps 16B alignment
    constexpr int H = COLS / 64;
    __shared__ float xs[BM * SK];

    const int tid = threadIdx.x;
    const int c4 = tid % C4;
    const int rg = tid / C4;
    const int n0 = blockIdx.x * BM;

    float4 acc[RPG];
#pragma unroll
    for (int j = 0; j < RPG; j++) acc[j] = make_float4(0.f, 0.f, 0.f, 0.f);

    for (int kb = 0; kb < K; kb += BK) {
        __syncthreads();
        // stage BM x 64 x-tile, coalesced float4 reads, b128 LDS writes
        constexpr int PASSES = BM * 16 / 256;
#pragma unroll
        for (int p = 0; p < PASSES; p++) {
            const int lin = p * 256 + tid;
            const int r = lin >> 4;
            const int f = lin & 15;
            float4 v = make_float4(0.f, 0.f, 0.f, 0.f);
            const int row = n0 + r;
            if (row < N)
                v = *reinterpret_cast<const float4*>(X + (size_t)row * K + kb + f * 4);
            *reinterpret_cast<float4*>(&xs[r * SK + f * 4]) = v;
        }
        __syncthreads();
#pragma unroll
        for (int kk = 0; kk < BK; kk += 4) {
            float4 wr0 = *reinterpret_cast<const float4*>(W + (size_t)(kb + kk + 0) * COLS + c4 * 4);
            float4 wr1 = *reinterpret_cast<const float4*>(W + (size_t)(kb + kk + 1) * COLS + c4 * 4);
            float4 wr2 = *reinterpret_cast<const float4*>(W + (size_t)(kb + kk + 2) * COLS + c4 * 4);
            float4 wr3 = *reinterpret_cast<const float4*>(W + (size_t)(kb + kk + 3) * COLS + c4 * 4);
#pragma unroll
            for (int j = 0; j < RPG; j++) {
                const float4 xv = *reinterpret_cast<const float4*>(&xs[(rg + NG * j) * SK + kk]);
                acc[j].x = fmaf(xv.x, wr0.x, acc[j].x);
                acc[j].y = fmaf(xv.x, wr0.y, acc[j].y);
                acc[j].z = fmaf(xv.x, wr0.z, acc[j].z);
                acc[j].w = fmaf(xv.x, wr0.w, acc[j].w);
                acc[j].x = fmaf(xv.y, wr1.x, acc[j].x);
                acc[j].y = fmaf(xv.y, wr1.y, acc[j].y);
                acc[j].z = fmaf(xv.y, wr1.z, acc[j].z);
                acc[j].w = fmaf(xv.y, wr1.w, acc[j].w);
                acc[j].x = fmaf(xv.z, wr2.x, acc[j].x);
                acc[j].y = fmaf(xv.z, wr2.y, acc[j].y);
                acc[j].z = fmaf(xv.z, wr2.z, acc[j].z);
                acc[j].w = fmaf(xv.z, wr2.w, acc[j].w);
                acc[j].x = fmaf(xv.w, wr3.x, acc[j].x);
                acc[j].y = fmaf(xv.w, wr3.y, acc[j].y);
                acc[j].z = fmaf(xv.w, wr3.z, acc[j].z);
                acc[j].w = fmaf(xv.w, wr3.w, acc[j].w);
            }
        }
    }

    const float4 as4 = *reinterpret_cast<const float4*>(att_src + c4 * 4);
    const float4 ad4 = *reinterpret_cast<const float4*>(att_dst + c4 * 4);

#pragma unroll
    for (int j = 0; j < RPG; j++) {
        const int row = n0 + rg + NG * j;
        float ps = acc[j].x * as4.x + acc[j].y * as4.y + acc[j].z * as4.z + acc[j].w * as4.w;
        float pd = acc[j].x * ad4.x + acc[j].y * ad4.y + acc[j].z * ad4.z + acc[j].w * ad4.w;
        // reduce across the 16 col-threads of each head (16-lane shfl groups)
#pragma unroll
        for (int off = 1; off < 16; off <<= 1) {
            ps += __shfl_xor(ps, off, 64);
            pd += __shfl_xor(pd, off, 64);
        }
        if (row < N) {
            *reinterpret_cast<float4*>(Z + (size_t)row * COLS + c4 * 4) = acc[j];
            if ((c4 & 15) == 0) {
                As[(size_t)row * H + (c4 >> 4)] = ps;
                Ad[(size_t)row * H + (c4 >> 4)] = pd;
            }
        }
    }
}

// ----------------------------- softmax + aggregate ---------------------------
// One block (256 thr) per destination node. Self-loop = virtual edge idx==deg.
// No max pass: exp args are O(10) here; identical math, fp32-safe.
template <int H, bool DO_ELU>
__global__ __launch_bounds__(256) void k_aggregate(
    const float* __restrict__ Z, const float* __restrict__ As, const float* __restrict__ Ad,
    const int* __restrict__ rowptr, const int* __restrict__ col,
    const float* __restrict__ bias, float* __restrict__ out, int N) {
    constexpr int COLS = H * 64;
    const int n = blockIdx.x;
    const int tid = threadIdx.x;
    const int start = rowptr[n];
    const int deg = rowptr[n + 1] - start;
    const int total = deg + 1;

    float adn[H];
#pragma unroll
    for (int h = 0; h < H; h++) adn[h] = Ad[(size_t)n * H + h];

    __shared__ float w_lds[64][H];
    __shared__ int off_lds[64];   // precomputed s*COLS

    float acc = 0.f, denom = 0.f;
    const int h = (H == 4) ? (tid >> 6) : 0;
    const int c = tid & 63;
    const int q = tid >> 6;

    for (int base = 0; base < total; base += 64) {
        const int cnt = min(64, total - base);
        __syncthreads();
        if (tid < cnt) {
            const int i = base + tid;
            const int s = (i < deg) ? col[start + i] : n;
            off_lds[tid] = s * COLS;
            if constexpr (H == 4) {
                const float4 av = *reinterpret_cast<const float4*>(As + (size_t)s * 4);
                w_lds[tid][0] = __expf(lrelu(av.x + adn[0]));
                w_lds[tid][1] = __expf(lrelu(av.y + adn[1]));
                w_lds[tid][2] = __expf(lrelu(av.z + adn[2]));
                w_lds[tid][3] = __expf(lrelu(av.w + adn[3]));
            } else {
                w_lds[tid][0] = __expf(lrelu(As[s] + adn[0]));
            }
        }
        __syncthreads();
        if constexpr (H == 4) {
            int j = 0;
            for (; j + 4 <= cnt; j += 4) {
                const int o0 = off_lds[j + 0], o1 = off_lds[j + 1];
                const int o2 = off_lds[j + 2], o3 = off_lds[j + 3];
                const float w0 = w_lds[j + 0][h], w1 = w_lds[j + 1][h];
                const float w2 = w_lds[j + 2][h], w3 = w_lds[j + 3][h];
                const float z0 = Z[o0 + tid], z1 = Z[o1 + tid];
                const float z2 = Z[o2 + tid], z3 = Z[o3 + tid];
                acc = fmaf(w0, z0, acc);
                acc = fmaf(w1, z1, acc);
                acc = fmaf(w2, z2, acc);
                acc = fmaf(w3, z3, acc);
                denom += (w0 + w1) + (w2 + w3);
            }
            for (; j < cnt; j++) {
                const float wj = w_lds[j][h];
                acc = fmaf(wj, Z[off_lds[j] + tid], acc);
                denom += wj;
            }
        } else {
            int j = q;
            for (; j + 8 <= cnt; j += 8) {
                const int o0 = off_lds[j], o1 = off_lds[j + 4];
                const float w0 = w_lds[j][0], w1 = w_lds[j + 4][0];
                const float z0 = Z[o0 + c], z1 = Z[o1 + c];
                acc = fmaf(w0, z0, acc);
                acc = fmaf(w1, z1, acc);
                denom += w0 + w1;
            }
            for (; j < cnt; j += 4) {
                const float wj = w_lds[j][0];
                acc = fmaf(wj, Z[off_lds[j] + c], acc);
                denom += wj;
            }
        }
    }

    if constexpr (H == 4) {
        float ov = acc / (denom + 1e-16f) + bias[tid];
        if (DO_ELU) ov = (ov > 0.f) ? ov : expm1f(ov);
        out[(size_t)n * COLS + tid] = ov;
    } else {
        __shared__ float accr[4][64];
        __shared__ float denr[4];
        accr[q][c] = acc;
        if (c == 0) denr[q] = denom;
        __syncthreads();
        if (tid < 64) {
            float tot = accr[0][tid] + accr[1][tid] + accr[2][tid] + accr[3][tid];
            float den = denr[0] + denr[1] + denr[2] + denr[3];
            float ov = tot / (den + 1e-16f) + bias[tid];
            if (DO_ELU) ov = (ov > 0.f) ? ov : expm1f(ov);
            out[(size_t)n * 64 + tid] = ov;
        }
    }
}

// ----------------------------- global max pool ------------------------------
__device__ __forceinline__ unsigned fenc(float f) {
    unsigned u = __float_as_uint(f);
    return (u & 0x80000000u) ? ~u : (u | 0x80000000u);
}

__global__ void k_segmax(const float* __restrict__ h2, const int* __restrict__ batch, int N,
                         unsigned* __restrict__ enc) {
    int id = blockIdx.x * 256 + threadIdx.x;
    if (id < N * 64) {
        int nn = id >> 6;
        int c = id & 63;
        int g = batch[nn];
        atomicMax(&enc[g * 64 + c], fenc(h2[id]));
    }
}

__global__ void k_decode(const unsigned* __restrict__ enc, float* __restrict__ out, int M) {
    int id = blockIdx.x * 256 + threadIdx.x;
    if (id < M) {
        unsigned e = enc[id];
        unsigned u = (e & 0x80000000u) ? (e & 0x7FFFFFFFu) : ~e;
        out[id] = __uint_as_float(u);
    }
}

// ----------------------------- launch ---------------------------------------
extern "C" void kernel_launch(void* const* d_in, const int* in_sizes, int n_in,
                              void* d_out, int out_size, void* d_ws, size_t ws_size,
                              hipStream_t stream) {
    const float* x = (const float*)d_in[0];
    const int* edge_index = (const int*)d_in[1];
    const int* batch = (const int*)d_in[2];
    const float* W0 = (const float*)d_in[3];
    const float* as0 = (const float*)d_in[4];
    const float* ad0 = (const float*)d_in[5];
    const float* b0 = (const float*)d_in[6];
    const float* W1 = (const float*)d_in[7];
    const float* as1 = (const float*)d_in[8];
    const float* ad1 = (const float*)d_in[9];
    const float* b1 = (const float*)d_in[10];
    const float* W2 = (const float*)d_in[11];
    const float* as2 = (const float*)d_in[12];
    const float* ad2 = (const float*)d_in[13];
    const float* b2 = (const float*)d_in[14];

    const int N = in_sizes[0] / 64;   // nodes
    const int E = in_sizes[1] / 2;    // edges (no self-loops)
    const int G = out_size / 64;      // graphs

    const int* srcs = edge_index;
    const int* dsts = edge_index + E;

    char* p = (char*)d_ws;
    auto alloc = [&](size_t bytes) {
        void* r = (void*)p;
        p += (bytes + 255) & ~(size_t)255;
        return r;
    };
    float* Z  = (float*)alloc((size_t)N * 256 * 4);  // GEMM output
    float* Hb = (float*)alloc((size_t)N * 256 * 4);  // hidden activations
    float* As = (float*)alloc((size_t)N * 4 * 4);
    float* Ad = (float*)alloc((size_t)N * 4 * 4);
    int* deg = (int*)alloc((size_t)N * 4);
    int* rowptr = (int*)alloc((size_t)(N + 1) * 4);
    int* cursor = (int*)alloc((size_t)N * 4);
    int* col = (int*)alloc((size_t)E * 4);
    unsigned* enc = (unsigned*)alloc((size_t)G * 64 * 4);

    hipMemsetAsync(deg, 0, (size_t)N * 4, stream);
    hipMemsetAsync(enc, 0, (size_t)G * 64 * 4, stream);

    const int eb = (E + 255) / 256;
    k_count<<<eb, 256, 0, stream>>>(dsts, E, deg);
    k_scan<<<1, 1024, 0, stream>>>(deg, rowptr, cursor, N);
    k_scatter<<<eb, 256, 0, stream>>>(srcs, dsts, E, cursor, col);

    // Layer 0: in 64, H=4 concat -> 256, ELU
    k_gemm_att<64, 256, 32><<<(N + 31) / 32, 256, 0, stream>>>(x, W0, as0, ad0, Z, As, Ad, N);
    k_aggregate<4, true><<<N, 256, 0, stream>>>(Z, As, Ad, rowptr, col, b0, Hb, N);
    // Layer 1: in 256, H=4 concat -> 256, ELU
    k_gemm_att<256, 256, 32><<<(N + 31) / 32, 256, 0, stream>>>(Hb, W1, as1, ad1, Z, As, Ad, N);
    k_aggregate<4, true><<<N, 256, 0, stream>>>(Z, As, Ad, rowptr, col, b1, Hb, N);
    // Layer 2: in 256, H=1 -> 64, no ELU
    k_gemm_att<256, 64, 64><<<(N + 63) / 64, 256, 0, stream>>>(Hb, W2, as2, ad2, Z, As, Ad, N);
    k_aggregate<1, false><<<N, 256, 0, stream>>>(Z, As, Ad, rowptr, col, b2, Hb, N);
    // Global max pool
    k_segmax<<<(N * 64 + 255) / 256, 256, 0, stream>>>(Hb, batch, N, enc);
    k_decode<<<(G * 64 + 255) / 256, 256, 0, stream>>>(enc, (float*)d_out, G * 64);
}

// Round 3
// 714.818 us; speedup vs baseline: 1.2736x; 1.2736x over previous
//
#include <hip/hip_runtime.h>
#include <math.h>

// ---------------------------------------------------------------------------
// GAT encoder: 3 GATConv layers (H=4,4,1) + ELU + global max pool.
// CSR-by-dst build once per call, then per layer:
//   gemm_att:  z = h @ W  (fp32, LDS x-tile, manual W double-buffer, capped
//              unroll to avoid VGPR spill), fused a_s/a_d epilogue
//   aggregate: per-node softmax (no max pass - exp args are O(10), fp32-safe)
//              + pipelined weighted gather; layer 2 fuses the pooled atomicMax
// Final: decode encoded max pool.
// ---------------------------------------------------------------------------

__device__ __forceinline__ float lrelu(float x) { return x > 0.f ? x : 0.2f * x; }

// ----------------------------- CSR build -----------------------------------
__global__ void k_count(const int* __restrict__ dst, int E, int* __restrict__ deg) {
    int e = blockIdx.x * 256 + threadIdx.x;
    if (e < E) atomicAdd(&deg[dst[e]], 1);
}

__global__ void k_scan(const int* __restrict__ deg, int* __restrict__ rowptr,
                       int* __restrict__ cursor, int N) {
    __shared__ int sums[1024];
    const int t = threadIdx.x;
    const int per = (N + 1023) >> 10;
    const int b0 = t * per;
    const int b1 = min(b0 + per, N);
    int s = 0;
    for (int i = b0; i < b1; i++) s += deg[i];
    sums[t] = s;
    __syncthreads();
    for (int off = 1; off < 1024; off <<= 1) {
        int v = (t >= off) ? sums[t - off] : 0;
        __syncthreads();
        sums[t] += v;
        __syncthreads();
    }
    int run = (t == 0) ? 0 : sums[t - 1];
    for (int i = b0; i < b1; i++) {
        rowptr[i] = run;
        cursor[i] = run;
        run += deg[i];
    }
    if (t == 1023) rowptr[N] = sums[1023];
}

__global__ void k_scatter(const int* __restrict__ src, const int* __restrict__ dst, int E,
                          int* __restrict__ cursor, int* __restrict__ col) {
    int e = blockIdx.x * 256 + threadIdx.x;
    if (e < E) {
        int p = atomicAdd(&cursor[dst[e]], 1);
        col[p] = src[e];
    }
}

// ----------------------------- GEMM + attention coefs -----------------------
// Z[N,COLS] = X[N,K] @ W[K,COLS]; a_s[n,h] = <z[n,h,:], att_src[h,:]>, same a_d.
// BM rows/block, 256 threads, thread owns 4 cols x RPG rows. W rows are
// double-buffered in registers (wc/wn), outer k-quad loop NOT unrolled so the
// register footprint stays ~115 (no spill). K must be a power of two.
template <int K, int COLS, int BM>
__global__ __launch_bounds__(256, 4) void k_gemm_att(
    const float* __restrict__ X, const float* __restrict__ W,
    const float* __restrict__ att_src, const float* __restrict__ att_dst,
    float* __restrict__ Z, float* __restrict__ As, float* __restrict__ Ad, int N) {
    constexpr int C4 = COLS / 4;     // threads per row-strip
    constexpr int NG = 256 / C4;     // row groups
    constexpr int RPG = BM / NG;     // rows per thread
    constexpr int BK = 64;
    constexpr int SK = BK + 4;       // LDS stride (floats), keeps 16B alignment
    constexpr int H = COLS / 64;
    __shared__ float xs[BM * SK];

    const int tid = threadIdx.x;
    const int c4 = tid % C4;
    const int rg = tid / C4;
    const int n0 = blockIdx.x * BM;

    float4 acc[RPG];
#pragma unroll
    for (int j = 0; j < RPG; j++) acc[j] = make_float4(0.f, 0.f, 0.f, 0.f);

    // W double buffer: wc holds the current k-quad's 4 rows (at this thread's
    // 4 columns), wn is the prefetch of the next quad.
    float4 wc[4], wn[4];
#pragma unroll
    for (int i = 0; i < 4; i++)
        wc[i] = *reinterpret_cast<const float4*>(W + (size_t)i * COLS + c4 * 4);

    for (int kb = 0; kb < K; kb += BK) {
        __syncthreads();
        // stage BM x 64 x-tile, coalesced float4 reads, b128 LDS writes
        constexpr int PASSES = BM / 16;
#pragma unroll
        for (int p = 0; p < PASSES; p++) {
            const int lin = p * 256 + tid;
            const int r = lin >> 4;
            const int f = lin & 15;
            float4 v = make_float4(0.f, 0.f, 0.f, 0.f);
            const int row = n0 + r;
            if (row < N)
                v = *reinterpret_cast<const float4*>(X + (size_t)row * K + kb + f * 4);
            *reinterpret_cast<float4*>(&xs[r * SK + f * 4]) = v;
        }
        __syncthreads();
#pragma unroll 1
        for (int kk = 0; kk < BK; kk += 4) {
            // prefetch next quad (wraps at K; the final wrap is harmless)
            const int kn = (kb + kk + 4) & (K - 1);
#pragma unroll
            for (int i = 0; i < 4; i++)
                wn[i] = *reinterpret_cast<const float4*>(W + (size_t)(kn + i) * COLS + c4 * 4);
#pragma unroll
            for (int j = 0; j < RPG; j++) {
                const float4 xv = *reinterpret_cast<const float4*>(&xs[(rg + NG * j) * SK + kk]);
                acc[j].x = fmaf(xv.x, wc[0].x, acc[j].x);
                acc[j].y = fmaf(xv.x, wc[0].y, acc[j].y);
                acc[j].z = fmaf(xv.x, wc[0].z, acc[j].z);
                acc[j].w = fmaf(xv.x, wc[0].w, acc[j].w);
                acc[j].x = fmaf(xv.y, wc[1].x, acc[j].x);
                acc[j].y = fmaf(xv.y, wc[1].y, acc[j].y);
                acc[j].z = fmaf(xv.y, wc[1].z, acc[j].z);
                acc[j].w = fmaf(xv.y, wc[1].w, acc[j].w);
                acc[j].x = fmaf(xv.z, wc[2].x, acc[j].x);
                acc[j].y = fmaf(xv.z, wc[2].y, acc[j].y);
                acc[j].z = fmaf(xv.z, wc[2].z, acc[j].z);
                acc[j].w = fmaf(xv.z, wc[2].w, acc[j].w);
                acc[j].x = fmaf(xv.w, wc[3].x, acc[j].x);
                acc[j].y = fmaf(xv.w, wc[3].y, acc[j].y);
                acc[j].z = fmaf(xv.w, wc[3].z, acc[j].z);
                acc[j].w = fmaf(xv.w, wc[3].w, acc[j].w);
            }
#pragma unroll
            for (int i = 0; i < 4; i++) wc[i] = wn[i];
        }
    }

    const float4 as4 = *reinterpret_cast<const float4*>(att_src + c4 * 4);
    const float4 ad4 = *reinterpret_cast<const float4*>(att_dst + c4 * 4);

#pragma unroll
    for (int j = 0; j < RPG; j++) {
        const int row = n0 + rg + NG * j;
        float ps = acc[j].x * as4.x + acc[j].y * as4.y + acc[j].z * as4.z + acc[j].w * as4.w;
        float pd = acc[j].x * ad4.x + acc[j].y * ad4.y + acc[j].z * ad4.z + acc[j].w * ad4.w;
        // reduce across the 16 col-threads of each head (16-lane shfl groups)
#pragma unroll
        for (int off = 1; off < 16; off <<= 1) {
            ps += __shfl_xor(ps, off, 64);
            pd += __shfl_xor(pd, off, 64);
        }
        if (row < N) {
            *reinterpret_cast<float4*>(Z + (size_t)row * COLS + c4 * 4) = acc[j];
            if ((c4 & 15) == 0) {
                As[(size_t)row * H + (c4 >> 4)] = ps;
                Ad[(size_t)row * H + (c4 >> 4)] = pd;
            }
        }
    }
}

// ----------------------------- global max pool helpers -----------------------
__device__ __forceinline__ unsigned fenc(float f) {
    unsigned u = __float_as_uint(f);
    return (u & 0x80000000u) ? ~u : (u | 0x80000000u);
}

// ----------------------------- softmax + aggregate ---------------------------
// One block (256 thr) per destination node. Self-loop = virtual edge idx==deg.
// No max pass: exp args are O(10) here; identical math, fp32-safe.
// POOL: instead of writing out[n,:], atomicMax into the encoded pool buffer.
template <int H, bool DO_ELU, bool POOL>
__global__ __launch_bounds__(256) void k_aggregate(
    const float* __restrict__ Z, const float* __restrict__ As, const float* __restrict__ Ad,
    const int* __restrict__ rowptr, const int* __restrict__ col,
    const float* __restrict__ bias, float* __restrict__ out,
    const int* __restrict__ batch, unsigned* __restrict__ enc, int N) {
    constexpr int COLS = H * 64;
    const int n = blockIdx.x;
    const int tid = threadIdx.x;
    const int start = rowptr[n];
    const int deg = rowptr[n + 1] - start;
    const int total = deg + 1;

    float adn[H];
#pragma unroll
    for (int h = 0; h < H; h++) adn[h] = Ad[(size_t)n * H + h];

    __shared__ float w_lds[64][H];
    __shared__ int off_lds[64];   // precomputed s*COLS

    float acc = 0.f, denom = 0.f;
    const int h = (H == 4) ? (tid >> 6) : 0;
    const int c = tid & 63;
    const int q = tid >> 6;

    for (int base = 0; base < total; base += 64) {
        const int cnt = min(64, total - base);
        __syncthreads();
        if (tid < cnt) {
            const int i = base + tid;
            const int s = (i < deg) ? col[start + i] : n;
            off_lds[tid] = s * COLS;
            if constexpr (H == 4) {
                const float4 av = *reinterpret_cast<const float4*>(As + (size_t)s * 4);
                w_lds[tid][0] = __expf(lrelu(av.x + adn[0]));
                w_lds[tid][1] = __expf(lrelu(av.y + adn[1]));
                w_lds[tid][2] = __expf(lrelu(av.z + adn[2]));
                w_lds[tid][3] = __expf(lrelu(av.w + adn[3]));
            } else {
                w_lds[tid][0] = __expf(lrelu(As[s] + adn[0]));
            }
        }
        __syncthreads();
        if constexpr (H == 4) {
            int j = 0;
            for (; j + 4 <= cnt; j += 4) {
                const int o0 = off_lds[j + 0], o1 = off_lds[j + 1];
                const int o2 = off_lds[j + 2], o3 = off_lds[j + 3];
                const float w0 = w_lds[j + 0][h], w1 = w_lds[j + 1][h];
                const float w2 = w_lds[j + 2][h], w3 = w_lds[j + 3][h];
                const float z0 = Z[o0 + tid], z1 = Z[o1 + tid];
                const float z2 = Z[o2 + tid], z3 = Z[o3 + tid];
                acc = fmaf(w0, z0, acc);
                acc = fmaf(w1, z1, acc);
                acc = fmaf(w2, z2, acc);
                acc = fmaf(w3, z3, acc);
                denom += (w0 + w1) + (w2 + w3);
            }
            for (; j < cnt; j++) {
                const float wj = w_lds[j][h];
                acc = fmaf(wj, Z[off_lds[j] + tid], acc);
                denom += wj;
            }
        } else {
            int j = q;
            for (; j + 8 <= cnt; j += 8) {
                const int o0 = off_lds[j], o1 = off_lds[j + 4];
                const float w0 = w_lds[j][0], w1 = w_lds[j + 4][0];
                const float z0 = Z[o0 + c], z1 = Z[o1 + c];
                acc = fmaf(w0, z0, acc);
                acc = fmaf(w1, z1, acc);
                denom += w0 + w1;
            }
            for (; j < cnt; j += 4) {
                const float wj = w_lds[j][0];
                acc = fmaf(wj, Z[off_lds[j] + c], acc);
                denom += wj;
            }
        }
    }

    if constexpr (H == 4) {
        float ov = acc / (denom + 1e-16f) + bias[tid];
        if (DO_ELU) ov = (ov > 0.f) ? ov : expm1f(ov);
        out[(size_t)n * COLS + tid] = ov;
    } else {
        __shared__ float accr[4][64];
        __shared__ float denr[4];
        accr[q][c] = acc;
        if (c == 0) denr[q] = denom;
        __syncthreads();
        if (tid < 64) {
            float tot = accr[0][tid] + accr[1][tid] + accr[2][tid] + accr[3][tid];
            float den = denr[0] + denr[1] + denr[2] + denr[3];
            float ov = tot / (den + 1e-16f) + bias[tid];
            if (DO_ELU) ov = (ov > 0.f) ? ov : expm1f(ov);
            if constexpr (POOL) {
                const int g = batch[n];
                atomicMax(&enc[g * 64 + tid], fenc(ov));
            } else {
                out[(size_t)n * 64 + tid] = ov;
            }
        }
    }
}

__global__ void k_decode(const unsigned* __restrict__ enc, float* __restrict__ out, int M) {
    int id = blockIdx.x * 256 + threadIdx.x;
    if (id < M) {
        unsigned e = enc[id];
        unsigned u = (e & 0x80000000u) ? (e & 0x7FFFFFFFu) : ~e;
        out[id] = __uint_as_float(u);
    }
}

// ----------------------------- launch ---------------------------------------
extern "C" void kernel_launch(void* const* d_in, const int* in_sizes, int n_in,
                              void* d_out, int out_size, void* d_ws, size_t ws_size,
                              hipStream_t stream) {
    const float* x = (const float*)d_in[0];
    const int* edge_index = (const int*)d_in[1];
    const int* batch = (const int*)d_in[2];
    const float* W0 = (const float*)d_in[3];
    const float* as0 = (const float*)d_in[4];
    const float* ad0 = (const float*)d_in[5];
    const float* b0 = (const float*)d_in[6];
    const float* W1 = (const float*)d_in[7];
    const float* as1 = (const float*)d_in[8];
    const float* ad1 = (const float*)d_in[9];
    const float* b1 = (const float*)d_in[10];
    const float* W2 = (const float*)d_in[11];
    const float* as2 = (const float*)d_in[12];
    const float* ad2 = (const float*)d_in[13];
    const float* b2 = (const float*)d_in[14];

    const int N = in_sizes[0] / 64;   // nodes
    const int E = in_sizes[1] / 2;    // edges (no self-loops)
    const int G = out_size / 64;      // graphs

    const int* srcs = edge_index;
    const int* dsts = edge_index + E;

    char* p = (char*)d_ws;
    auto alloc = [&](size_t bytes) {
        void* r = (void*)p;
        p += (bytes + 255) & ~(size_t)255;
        return r;
    };
    float* Z  = (float*)alloc((size_t)N * 256 * 4);  // GEMM output
    float* Hb = (float*)alloc((size_t)N * 256 * 4);  // hidden activations
    float* As = (float*)alloc((size_t)N * 4 * 4);
    float* Ad = (float*)alloc((size_t)N * 4 * 4);
    int* deg = (int*)alloc((size_t)N * 4);
    int* rowptr = (int*)alloc((size_t)(N + 1) * 4);
    int* cursor = (int*)alloc((size_t)N * 4);
    int* col = (int*)alloc((size_t)E * 4);
    unsigned* enc = (unsigned*)alloc((size_t)G * 64 * 4);

    hipMemsetAsync(deg, 0, (size_t)N * 4, stream);
    hipMemsetAsync(enc, 0, (size_t)G * 64 * 4, stream);

    const int eb = (E + 255) / 256;
    k_count<<<eb, 256, 0, stream>>>(dsts, E, deg);
    k_scan<<<1, 1024, 0, stream>>>(deg, rowptr, cursor, N);
    k_scatter<<<eb, 256, 0, stream>>>(srcs, dsts, E, cursor, col);

    // Layer 0: in 64, H=4 concat -> 256, ELU
    k_gemm_att<64, 256, 32><<<(N + 31) / 32, 256, 0, stream>>>(x, W0, as0, ad0, Z, As, Ad, N);
    k_aggregate<4, true, false><<<N, 256, 0, stream>>>(Z, As, Ad, rowptr, col, b0, Hb,
                                                       nullptr, nullptr, N);
    // Layer 1: in 256, H=4 concat -> 256, ELU
    k_gemm_att<256, 256, 32><<<(N + 31) / 32, 256, 0, stream>>>(Hb, W1, as1, ad1, Z, As, Ad, N);
    k_aggregate<4, true, false><<<N, 256, 0, stream>>>(Z, As, Ad, rowptr, col, b1, Hb,
                                                       nullptr, nullptr, N);
    // Layer 2: in 256, H=1 -> 64, no ELU, fused global max pool
    k_gemm_att<256, 64, 64><<<(N + 63) / 64, 256, 0, stream>>>(Hb, W2, as2, ad2, Z, As, Ad, N);
    k_aggregate<1, false, true><<<N, 256, 0, stream>>>(Z, As, Ad, rowptr, col, b2, nullptr,
                                                       batch, enc, N);
    // Decode pooled maxima
    k_decode<<<(G * 64 + 255) / 256, 256, 0, stream>>>(enc, (float*)d_out, G * 64);
}

// Round 4
// 671.448 us; speedup vs baseline: 1.3559x; 1.0646x over previous
//
#include <hip/hip_runtime.h>
#include <math.h>

// ---------------------------------------------------------------------------
// GAT encoder: 3 GATConv layers (H=4,4,1) + ELU + global max pool.
// CSR-by-dst build once per call, then per layer:
//   gemm_att:  z = h @ W  (fp32, LDS x-tile, manual W double-buffer, capped
//              unroll to avoid VGPR spill), fused a_s/a_d epilogue
//   aggregate: wave-per-(node,head), wave-synchronous softmax+gather:
//              lane j holds edge j's weight, readlane broadcasts (SGPR) drive
//              an 8-deep pipelined row gather. No LDS, no __syncthreads.
//              Layer 2 fuses the pooled atomicMax.
// Final: decode encoded max pool.
// ---------------------------------------------------------------------------

__device__ __forceinline__ float lrelu(float x) { return x > 0.f ? x : 0.2f * x; }

__device__ __forceinline__ float readlane_f(float v, int l) {
    return __uint_as_float((unsigned)__builtin_amdgcn_readlane((int)__float_as_uint(v), l));
}

// ----------------------------- CSR build -----------------------------------
__global__ void k_count(const int* __restrict__ dst, int E, int* __restrict__ deg) {
    int e = blockIdx.x * 256 + threadIdx.x;
    if (e < E) atomicAdd(&deg[dst[e]], 1);
}

__global__ void k_scan(const int* __restrict__ deg, int* __restrict__ rowptr,
                       int* __restrict__ cursor, int N) {
    __shared__ int sums[1024];
    const int t = threadIdx.x;
    const int per = (N + 1023) >> 10;
    const int b0 = t * per;
    const int b1 = min(b0 + per, N);
    int s = 0;
    for (int i = b0; i < b1; i++) s += deg[i];
    sums[t] = s;
    __syncthreads();
    for (int off = 1; off < 1024; off <<= 1) {
        int v = (t >= off) ? sums[t - off] : 0;
        __syncthreads();
        sums[t] += v;
        __syncthreads();
    }
    int run = (t == 0) ? 0 : sums[t - 1];
    for (int i = b0; i < b1; i++) {
        rowptr[i] = run;
        cursor[i] = run;
        run += deg[i];
    }
    if (t == 1023) rowptr[N] = sums[1023];
}

__global__ void k_scatter(const int* __restrict__ src, const int* __restrict__ dst, int E,
                          int* __restrict__ cursor, int* __restrict__ col) {
    int e = blockIdx.x * 256 + threadIdx.x;
    if (e < E) {
        int p = atomicAdd(&cursor[dst[e]], 1);
        col[p] = src[e];
    }
}

// ----------------------------- GEMM + attention coefs -----------------------
// Z[N,COLS] = X[N,K] @ W[K,COLS]; a_s[n,h] = <z[n,h,:], att_src[h,:]>, same a_d.
// BM rows/block, 256 threads, thread owns 4 cols x RPG rows. W rows are
// double-buffered in registers (wc/wn), outer k-quad loop NOT unrolled so the
// register footprint stays ~115 (no spill). K must be a power of two.
template <int K, int COLS, int BM>
__global__ __launch_bounds__(256, 4) void k_gemm_att(
    const float* __restrict__ X, const float* __restrict__ W,
    const float* __restrict__ att_src, const float* __restrict__ att_dst,
    float* __restrict__ Z, float* __restrict__ As, float* __restrict__ Ad, int N) {
    constexpr int C4 = COLS / 4;     // threads per row-strip
    constexpr int NG = 256 / C4;     // row groups
    constexpr int RPG = BM / NG;     // rows per thread
    constexpr int BK = 64;
    constexpr int SK = BK + 4;       // LDS stride (floats), keeps 16B alignment
    constexpr int H = COLS / 64;
    __shared__ float xs[BM * SK];

    const int tid = threadIdx.x;
    const int c4 = tid % C4;
    const int rg = tid / C4;
    const int n0 = blockIdx.x * BM;

    float4 acc[RPG];
#pragma unroll
    for (int j = 0; j < RPG; j++) acc[j] = make_float4(0.f, 0.f, 0.f, 0.f);

    float4 wc[4], wn[4];
#pragma unroll
    for (int i = 0; i < 4; i++)
        wc[i] = *reinterpret_cast<const float4*>(W + (size_t)i * COLS + c4 * 4);

    for (int kb = 0; kb < K; kb += BK) {
        __syncthreads();
        constexpr int PASSES = BM / 16;
#pragma unroll
        for (int p = 0; p < PASSES; p++) {
            const int lin = p * 256 + tid;
            const int r = lin >> 4;
            const int f = lin & 15;
            float4 v = make_float4(0.f, 0.f, 0.f, 0.f);
            const int row = n0 + r;
            if (row < N)
                v = *reinterpret_cast<const float4*>(X + (size_t)row * K + kb + f * 4);
            *reinterpret_cast<float4*>(&xs[r * SK + f * 4]) = v;
        }
        __syncthreads();
#pragma unroll 1
        for (int kk = 0; kk < BK; kk += 4) {
            const int kn = (kb + kk + 4) & (K - 1);
#pragma unroll
            for (int i = 0; i < 4; i++)
                wn[i] = *reinterpret_cast<const float4*>(W + (size_t)(kn + i) * COLS + c4 * 4);
#pragma unroll
            for (int j = 0; j < RPG; j++) {
                const float4 xv = *reinterpret_cast<const float4*>(&xs[(rg + NG * j) * SK + kk]);
                acc[j].x = fmaf(xv.x, wc[0].x, acc[j].x);
                acc[j].y = fmaf(xv.x, wc[0].y, acc[j].y);
                acc[j].z = fmaf(xv.x, wc[0].z, acc[j].z);
                acc[j].w = fmaf(xv.x, wc[0].w, acc[j].w);
                acc[j].x = fmaf(xv.y, wc[1].x, acc[j].x);
                acc[j].y = fmaf(xv.y, wc[1].y, acc[j].y);
                acc[j].z = fmaf(xv.y, wc[1].z, acc[j].z);
                acc[j].w = fmaf(xv.y, wc[1].w, acc[j].w);
                acc[j].x = fmaf(xv.z, wc[2].x, acc[j].x);
                acc[j].y = fmaf(xv.z, wc[2].y, acc[j].y);
                acc[j].z = fmaf(xv.z, wc[2].z, acc[j].z);
                acc[j].w = fmaf(xv.z, wc[2].w, acc[j].w);
                acc[j].x = fmaf(xv.w, wc[3].x, acc[j].x);
                acc[j].y = fmaf(xv.w, wc[3].y, acc[j].y);
                acc[j].z = fmaf(xv.w, wc[3].z, acc[j].z);
                acc[j].w = fmaf(xv.w, wc[3].w, acc[j].w);
            }
#pragma unroll
            for (int i = 0; i < 4; i++) wc[i] = wn[i];
        }
    }

    const float4 as4 = *reinterpret_cast<const float4*>(att_src + c4 * 4);
    const float4 ad4 = *reinterpret_cast<const float4*>(att_dst + c4 * 4);

#pragma unroll
    for (int j = 0; j < RPG; j++) {
        const int row = n0 + rg + NG * j;
        float ps = acc[j].x * as4.x + acc[j].y * as4.y + acc[j].z * as4.z + acc[j].w * as4.w;
        float pd = acc[j].x * ad4.x + acc[j].y * ad4.y + acc[j].z * ad4.z + acc[j].w * ad4.w;
#pragma unroll
        for (int off = 1; off < 16; off <<= 1) {
            ps += __shfl_xor(ps, off, 64);
            pd += __shfl_xor(pd, off, 64);
        }
        if (row < N) {
            *reinterpret_cast<float4*>(Z + (size_t)row * COLS + c4 * 4) = acc[j];
            if ((c4 & 15) == 0) {
                As[(size_t)row * H + (c4 >> 4)] = ps;
                Ad[(size_t)row * H + (c4 >> 4)] = pd;
            }
        }
    }
}

// ----------------------------- global max pool helpers -----------------------
__device__ __forceinline__ unsigned fenc(float f) {
    unsigned u = __float_as_uint(f);
    return (u & 0x80000000u) ? ~u : (u | 0x80000000u);
}

// ----------------------------- softmax + aggregate ---------------------------
// Wave-synchronous: one wave per (node, head). H=4: block = 4 heads of node
// blockIdx. H=1: block = 4 consecutive nodes. Lane j computes edge j's softmax
// weight; readlane (SGPR broadcast) drives an 8-deep pipelined row gather.
// Self-loop = virtual edge idx==deg. No max pass (exp args O(10), fp32-safe).
template <int H, bool DO_ELU, bool POOL>
__global__ __launch_bounds__(256) void k_aggregate(
    const float* __restrict__ Z, const float* __restrict__ As, const float* __restrict__ Ad,
    const int* __restrict__ rowptr, const int* __restrict__ col,
    const float* __restrict__ bias, float* __restrict__ out,
    const int* __restrict__ batch, unsigned* __restrict__ enc, int N) {
    constexpr int COLS = H * 64;
    const int tid = threadIdx.x;
    const int wv = tid >> 6;
    const int lane = tid & 63;

    int n, h;
    if constexpr (H == 4) {
        n = blockIdx.x;
        h = wv;
    } else {
        n = blockIdx.x * 4 + wv;
        h = 0;
        if (n >= N) return;
    }

    const int start = rowptr[n];
    const int deg = rowptr[n + 1] - start;
    const int total = deg + 1;
    const float adn = Ad[(size_t)n * H + h];
    const float* __restrict__ Zc = Z + h * 64 + lane;

    float acc = 0.f, denom = 0.f;

    for (int base = 0; base < total; base += 64) {
        const int cnt = min(64, total - base);
        const int i = base + lane;
        int s = n;
        if (i < deg) s = col[start + i];
        float w = 0.f;
        if (i < total) w = __expf(lrelu(As[(size_t)s * H + h] + adn));

        int jj = 0;
        for (; jj + 8 <= cnt; jj += 8) {
            int sb[8];
            float wb[8], zb[8];
#pragma unroll
            for (int u = 0; u < 8; u++) {
                sb[u] = __builtin_amdgcn_readlane(s, jj + u);
                wb[u] = readlane_f(w, jj + u);
            }
#pragma unroll
            for (int u = 0; u < 8; u++) zb[u] = Zc[(size_t)sb[u] * COLS];
#pragma unroll
            for (int u = 0; u < 8; u++) {
                acc = fmaf(wb[u], zb[u], acc);
                denom += wb[u];
            }
        }
        for (; jj + 4 <= cnt; jj += 4) {
            int sb[4];
            float wb[4], zb[4];
#pragma unroll
            for (int u = 0; u < 4; u++) {
                sb[u] = __builtin_amdgcn_readlane(s, jj + u);
                wb[u] = readlane_f(w, jj + u);
            }
#pragma unroll
            for (int u = 0; u < 4; u++) zb[u] = Zc[(size_t)sb[u] * COLS];
#pragma unroll
            for (int u = 0; u < 4; u++) {
                acc = fmaf(wb[u], zb[u], acc);
                denom += wb[u];
            }
        }
        for (; jj < cnt; jj++) {
            const int s0 = __builtin_amdgcn_readlane(s, jj);
            const float w0 = readlane_f(w, jj);
            acc = fmaf(w0, Zc[(size_t)s0 * COLS], acc);
            denom += w0;
        }
    }

    float ov = acc / (denom + 1e-16f) + bias[h * 64 + lane];
    if (DO_ELU) ov = (ov > 0.f) ? ov : expm1f(ov);

    if constexpr (POOL) {
        const int g = batch[n];
        atomicMax(&enc[g * 64 + lane], fenc(ov));
    } else {
        out[(size_t)n * COLS + h * 64 + lane] = ov;
    }
}

__global__ void k_decode(const unsigned* __restrict__ enc, float* __restrict__ out, int M) {
    int id = blockIdx.x * 256 + threadIdx.x;
    if (id < M) {
        unsigned e = enc[id];
        unsigned u = (e & 0x80000000u) ? (e & 0x7FFFFFFFu) : ~e;
        out[id] = __uint_as_float(u);
    }
}

// ----------------------------- launch ---------------------------------------
extern "C" void kernel_launch(void* const* d_in, const int* in_sizes, int n_in,
                              void* d_out, int out_size, void* d_ws, size_t ws_size,
                              hipStream_t stream) {
    const float* x = (const float*)d_in[0];
    const int* edge_index = (const int*)d_in[1];
    const int* batch = (const int*)d_in[2];
    const float* W0 = (const float*)d_in[3];
    const float* as0 = (const float*)d_in[4];
    const float* ad0 = (const float*)d_in[5];
    const float* b0 = (const float*)d_in[6];
    const float* W1 = (const float*)d_in[7];
    const float* as1 = (const float*)d_in[8];
    const float* ad1 = (const float*)d_in[9];
    const float* b1 = (const float*)d_in[10];
    const float* W2 = (const float*)d_in[11];
    const float* as2 = (const float*)d_in[12];
    const float* ad2 = (const float*)d_in[13];
    const float* b2 = (const float*)d_in[14];

    const int N = in_sizes[0] / 64;   // nodes
    const int E = in_sizes[1] / 2;    // edges (no self-loops)
    const int G = out_size / 64;      // graphs

    const int* srcs = edge_index;
    const int* dsts = edge_index + E;

    char* p = (char*)d_ws;
    auto alloc = [&](size_t bytes) {
        void* r = (void*)p;
        p += (bytes + 255) & ~(size_t)255;
        return r;
    };
    float* Z  = (float*)alloc((size_t)N * 256 * 4);  // GEMM output
    float* Hb = (float*)alloc((size_t)N * 256 * 4);  // hidden activations
    float* As = (float*)alloc((size_t)N * 4 * 4);
    float* Ad = (float*)alloc((size_t)N * 4 * 4);
    int* deg = (int*)alloc((size_t)N * 4);
    int* rowptr = (int*)alloc((size_t)(N + 1) * 4);
    int* cursor = (int*)alloc((size_t)N * 4);
    int* col = (int*)alloc((size_t)E * 4);
    unsigned* enc = (unsigned*)alloc((size_t)G * 64 * 4);

    hipMemsetAsync(deg, 0, (size_t)N * 4, stream);
    hipMemsetAsync(enc, 0, (size_t)G * 64 * 4, stream);

    const int eb = (E + 255) / 256;
    k_count<<<eb, 256, 0, stream>>>(dsts, E, deg);
    k_scan<<<1, 1024, 0, stream>>>(deg, rowptr, cursor, N);
    k_scatter<<<eb, 256, 0, stream>>>(srcs, dsts, E, cursor, col);

    // Layer 0: in 64, H=4 concat -> 256, ELU
    k_gemm_att<64, 256, 32><<<(N + 31) / 32, 256, 0, stream>>>(x, W0, as0, ad0, Z, As, Ad, N);
    k_aggregate<4, true, false><<<N, 256, 0, stream>>>(Z, As, Ad, rowptr, col, b0, Hb,
                                                       nullptr, nullptr, N);
    // Layer 1: in 256, H=4 concat -> 256, ELU
    k_gemm_att<256, 256, 32><<<(N + 31) / 32, 256, 0, stream>>>(Hb, W1, as1, ad1, Z, As, Ad, N);
    k_aggregate<4, true, false><<<N, 256, 0, stream>>>(Z, As, Ad, rowptr, col, b1, Hb,
                                                       nullptr, nullptr, N);
    // Layer 2: in 256, H=1 -> 64, no ELU, fused global max pool
    k_gemm_att<256, 64, 64><<<(N + 63) / 64, 256, 0, stream>>>(Hb, W2, as2, ad2, Z, As, Ad, N);
    k_aggregate<1, false, true><<<(N + 3) / 4, 256, 0, stream>>>(Z, As, Ad, rowptr, col, b2,
                                                                 nullptr, batch, enc, N);
    // Decode pooled maxima
    k_decode<<<(G * 64 + 255) / 256, 256, 0, stream>>>(enc, (float*)d_out, G * 64);
}